// Round 33
// baseline (183.349 us; speedup 1.0000x reference)
//
#include <hip/hip_runtime.h>
#include <stdint.h>

#define NN 1024
#define DD 256
#define KHOPS 8

typedef unsigned short u16;
typedef unsigned long long u64;
typedef unsigned char u8;
typedef float f32x4v __attribute__((ext_vector_type(4)));

__device__ __forceinline__ float b2f(u16 u){ return __uint_as_float(((unsigned int)u) << 16); }
__device__ __forceinline__ u16 f2b(float f){
  unsigned int x = __float_as_uint(f);
  unsigned int r = (x + 0x7FFFu + ((x >> 16) & 1u)) >> 16;
  return (u16)r;
}
__device__ __forceinline__ float wsum(float v){
  #pragma unroll
  for(int off = 32; off >= 1; off >>= 1) v += __shfl_xor(v, off, 64);
  return v;
}

// ---------------- sentinel fill (contract-violation signal), f32
__global__ __launch_bounds__(256) void k_fill(float* p, unsigned n, float v){
  unsigned idx = blockIdx.x * 256 + threadIdx.x;
  if(idx < n) p[idx] = v;
}

// ---------------- merged prelude: blocks 0..383 = staging GEMM, 384..1407 = bitset+nlist
__global__ __launch_bounds__(256) void k_prep(const float* X, const float* Wq, const float* Wk,
                                              const float* Wv, float* qf, float* kf, u16* vb,
                                              const int* adj, u64* bits, u16* nlistg, int* cntg){
  __shared__ float xs[32][256];
  int t = threadIdx.x;
  if(blockIdx.x >= 384){
    int vblk = blockIdx.x - 384;
    int row = vblk * 4 + (t >> 6);
    int lane = t & 63;
    const int* ar = adj + (size_t)row * NN;
    u64 myw = 0;
    #pragma unroll
    for(int w = 0; w < 16; w++){
      u64 msk = __ballot(ar[w * 64 + lane] != 0);
      if(lane == 0) bits[(size_t)row * 16 + w] = msk;
      if(lane == w) myw = msk;
    }
    int pc = (lane < 16) ? __popcll(myw) : 0;
    int inc = pc;
    #pragma unroll
    for(int off = 1; off < 64; off <<= 1){ int u = __shfl_up(inc, off, 64); if(lane >= off) inc += u; }
    int base = inc - pc;
    int total = __shfl(inc, 63, 64);
    if(lane < 16){
      u64 w = myw;
      int pos = base;
      while(w){
        int bpos = __builtin_ctzll(w);
        if(pos < 64) nlistg[(size_t)row * 64 + pos] = (u16)(lane * 64 + bpos);
        pos++;
        w &= w - 1;
      }
    }
    if(lane == 0) cntg[row] = total;
    return;
  }
  int proj = blockIdx.x >> 7;
  int rb = blockIdx.x & 127;
  const float* W = (proj == 0) ? Wq : (proj == 1) ? Wk : Wv;
  const float* Xb = X + (size_t)rb * 32 * 256;
  #pragma unroll
  for(int m = 0; m < 32; m++) xs[m][t] = Xb[m * 256 + t];
  __syncthreads();
  float acc[32];
  #pragma unroll
  for(int r = 0; r < 32; r++) acc[r] = 0.f;
  for(int k4 = 0; k4 < 64; k4++){
    float w0 = W[(size_t)(k4 * 4 + 0) * 256 + t];
    float w1 = W[(size_t)(k4 * 4 + 1) * 256 + t];
    float w2 = W[(size_t)(k4 * 4 + 2) * 256 + t];
    float w3 = W[(size_t)(k4 * 4 + 3) * 256 + t];
    #pragma unroll
    for(int r = 0; r < 32; r++){
      float4 xv = *(const float4*)&xs[r][k4 * 4];
      acc[r] = fmaf(xv.x, w0, fmaf(xv.y, w1, fmaf(xv.z, w2, fmaf(xv.w, w3, acc[r]))));
    }
  }
  int rowbase = rb * 32;
  if(proj == 2){
    for(int r = 0; r < 32; r++) vb[(size_t)(rowbase + r) * 256 + t] = f2b(acc[r]);
  } else {
    float* dst = (proj == 0) ? qf : kf;
    for(int r = 0; r < 32; r++) dst[(size_t)(rowbase + r) * 256 + t] = acc[r];
  }
}

// ---------------- frontier BFS with LDS-resident adjacency (R29-verbatim, 512 thr)
__global__ __launch_bounds__(512) void k_bfs(const u64* bits, u8* dist, float* expl){
  __shared__ __attribute__((aligned(16))) u64 asw[16384];
  __shared__ __attribute__((aligned(16))) u8 drow4[8][1024];
  __shared__ u64 red4[8][16];
  int tid = threadIdx.x;
  int wv = tid >> 6, lane = tid & 63;
  int batch = blockIdx.x >> 6;
  int rowbase = (blockIdx.x & 63) * 16;
  const u64* bb = bits + (((size_t)batch << 10)) * 16;
  for(int g = tid; g < 8192; g += 512){
    int j = g >> 3, c = g & 7;
    ulonglong2 v = *(const ulonglong2*)(bb + (size_t)j * 16 + c * 2);
    int ce = c ^ (j & 7);
    *(ulonglong2*)(&asw[j * 16 + ce * 2]) = v;
  }
  __syncthreads();
  int s = lane & 7;
  for(int rr = 0; rr < 2; rr++){
    int row_local = rowbase + wv * 2 + rr;
    int row = (batch << 10) + row_local;
    u64 vis[16], cur[16];
    {
      const u64* p = asw + row_local * 16;
      int sr = row_local & 7;
      #pragma unroll
      for(int c = 0; c < 8; c++){
        ulonglong2 v = *(const ulonglong2*)(p + (((c ^ sr)) << 1));
        vis[2*c] = v.x; vis[2*c+1] = v.y;
        cur[2*c] = v.x; cur[2*c+1] = v.y;
      }
    }
    { int4 ff; ff.x = ff.y = ff.z = ff.w = -1; ((int4*)drow4[wv])[lane] = ff; }
    __builtin_amdgcn_wave_barrier();
    #pragma unroll
    for(int it = 0; it < 16; it++)
      if((cur[it] >> lane) & 1) drow4[wv][it * 64 + lane] = 0;
    for(int k = 1; k < KHOPS; k++){
      unsigned mymask = 0;
      #pragma unroll
      for(int it = 0; it < 16; it++) mymask |= ((unsigned)((cur[it] >> lane) & 1)) << it;
      u64 acc[16];
      #pragma unroll
      for(int w = 0; w < 16; w++) acc[w] = 0;
      while(mymask){
        int it0 = __builtin_ctz(mymask); mymask &= mymask - 1;
        int it1 = it0;
        if(mymask){ it1 = __builtin_ctz(mymask); mymask &= mymask - 1; }
        const u64* pA = asw + (it0 * 64 + lane) * 16;
        const u64* pB = asw + (it1 * 64 + lane) * 16;
        ulonglong2 a0 = *(const ulonglong2*)(pA + ((0^s)<<1)), b0 = *(const ulonglong2*)(pB + ((0^s)<<1));
        ulonglong2 a1 = *(const ulonglong2*)(pA + ((1^s)<<1)), b1 = *(const ulonglong2*)(pB + ((1^s)<<1));
        ulonglong2 a2 = *(const ulonglong2*)(pA + ((2^s)<<1)), b2 = *(const ulonglong2*)(pB + ((2^s)<<1));
        ulonglong2 a3 = *(const ulonglong2*)(pA + ((3^s)<<1)), b3 = *(const ulonglong2*)(pB + ((3^s)<<1));
        ulonglong2 a4 = *(const ulonglong2*)(pA + ((4^s)<<1)), b4 = *(const ulonglong2*)(pB + ((4^s)<<1));
        ulonglong2 a5 = *(const ulonglong2*)(pA + ((5^s)<<1)), b5 = *(const ulonglong2*)(pB + ((5^s)<<1));
        ulonglong2 a6 = *(const ulonglong2*)(pA + ((6^s)<<1)), b6 = *(const ulonglong2*)(pB + ((6^s)<<1));
        ulonglong2 a7 = *(const ulonglong2*)(pA + ((7^s)<<1)), b7 = *(const ulonglong2*)(pB + ((7^s)<<1));
        acc[0]  |= a0.x | b0.x;  acc[1]  |= a0.y | b0.y;
        acc[2]  |= a1.x | b1.x;  acc[3]  |= a1.y | b1.y;
        acc[4]  |= a2.x | b2.x;  acc[5]  |= a2.y | b2.y;
        acc[6]  |= a3.x | b3.x;  acc[7]  |= a3.y | b3.y;
        acc[8]  |= a4.x | b4.x;  acc[9]  |= a4.y | b4.y;
        acc[10] |= a5.x | b5.x;  acc[11] |= a5.y | b5.y;
        acc[12] |= a6.x | b6.x;  acc[13] |= a6.y | b6.y;
        acc[14] |= a7.x | b7.x;  acc[15] |= a7.y | b7.y;
      }
      #pragma unroll
      for(int w = 0; w < 16; w++){
        acc[w] |= __shfl_xor(acc[w], 16, 64);
        acc[w] |= __shfl_xor(acc[w], 32, 64);
      }
      int g4 = lane >> 4;
      u64 r0, r1, r2, r3;
      if(g4 == 0){ r0 = acc[0];  r1 = acc[1];  r2 = acc[2];  r3 = acc[3];  }
      else if(g4 == 1){ r0 = acc[4];  r1 = acc[5];  r2 = acc[6];  r3 = acc[7];  }
      else if(g4 == 2){ r0 = acc[8];  r1 = acc[9];  r2 = acc[10]; r3 = acc[11]; }
      else            { r0 = acc[12]; r1 = acc[13]; r2 = acc[14]; r3 = acc[15]; }
      #pragma unroll
      for(int off = 1; off <= 8; off <<= 1){
        r0 |= __shfl_xor(r0, off, 64);
        r1 |= __shfl_xor(r1, off, 64);
        r2 |= __shfl_xor(r2, off, 64);
        r3 |= __shfl_xor(r3, off, 64);
      }
      int sub = lane & 15;
      if(sub == 0)      red4[wv][g4 * 4 + 0] = r0;
      else if(sub == 1) red4[wv][g4 * 4 + 1] = r1;
      else if(sub == 2) red4[wv][g4 * 4 + 2] = r2;
      else if(sub == 3) red4[wv][g4 * 4 + 3] = r3;
      __builtin_amdgcn_wave_barrier();
      u64 any = 0, andv = ~0ull;
      #pragma unroll
      for(int w = 0; w < 16; w++){
        u64 nv = red4[wv][w];
        u64 nw = nv & ~vis[w];
        vis[w] |= nw;
        cur[w] = nw;
        any |= nw;
        andv &= vis[w];
      }
      __builtin_amdgcn_wave_barrier();
      if(any == 0) break;
      #pragma unroll
      for(int it = 0; it < 16; it++)
        if((cur[it] >> lane) & 1) drow4[wv][it * 64 + lane] = (u8)k;
      if(andv == ~0ull) break;
    }
    __builtin_amdgcn_wave_barrier();
    ((int4*)(dist + (size_t)row * NN))[lane] = ((const int4*)drow4[wv])[lane];
    float* eo = expl + (size_t)row * NN;
    #pragma unroll
    for(int it = 0; it < 16; it++){
      int j = it * 64 + lane;
      eo[j] = ((vis[it] >> lane) & 1) ? 1.0f : 0.0f;
    }
  }
}

// ---------------- FUSED bias + attention: 512 threads, ONE head per wave (8 waves)
__global__ __launch_bounds__(512) void k_biasattn(
    const u64* bits, const float* ea, const u8* dist, const float* dw,
    const float* qf, const float* kf, const u16* vb,
    const u16* nlistg, const int* cntg,
    float* ab_out, float* ao, float* fvals)
{
  __shared__ float qs[256];
  __shared__ u16 nlist[1024];
  __shared__ float sc[8][64];
  __shared__ float evl[8][64];
  __shared__ float w8s[8][8];          // w8s[h][k] = dw[k][h]
  int t = threadIdx.x, wv = t >> 6, lane = t & 63;
  int bi = blockIdx.x, b = bi >> 10, i = bi & 1023;
  if(t < 256) qs[t] = qf[(size_t)bi * 256 + t];
  if(t < 64) w8s[t & 7][t >> 3] = dw[(t >> 3) * 8 + (t & 7)];
  int cnt = cntg[bi];
  if(t < 64 && t < cnt) nlist[t] = nlistg[(size_t)bi * 64 + t];
  __syncthreads();
  // rare fallback: cnt > 64 needs full nlist, rebuild from bits (block-uniform branch)
  if(cnt > 64){
    if(wv == 0){
      __shared__ u64 wm_f[16];
      __shared__ int bs_f[16];
      if(lane < 16) wm_f[lane] = bits[(size_t)bi * 16 + lane];
      __builtin_amdgcn_wave_barrier();
      if(lane == 0){
        int run = 0;
        #pragma unroll
        for(int it = 0; it < 16; it++){ bs_f[it] = run; run += __popcll(wm_f[it]); }
      }
      __builtin_amdgcn_wave_barrier();
      if(lane < 16){
        u64 w = wm_f[lane];
        int pos = bs_f[lane];
        while(w){
          int bpos = __builtin_ctzll(w);
          nlist[pos++] = (u16)(lane * 64 + bpos);
          w &= w - 1;
        }
      }
    }
    __syncthreads();
  }
  const float scale = 0.17677669529663687f;   // 1/sqrt(32)
  int d = lane & 31;
  int half = lane >> 5;
  bool isV = (lane >= 32);
  int g8 = lane >> 3, r8 = lane & 7;
  size_t kvbase = ((size_t)(b << 10)) * 256;
  const u8* drow = dist + (size_t)bi * NN;
  float* aorow = ao + (size_t)bi * 256;
  int h = wv;                                 // one head per wave
  int widx = (((b << 3) + h) << 10) + i;
  const float* earow = ea + (size_t)widx * NN;
  float* abrow = ab_out + (size_t)widx * NN;
  // ---- phase A: single-head bias stream (cached ea loads; NT ab stores)
  float fpart = 0.f;
  #pragma unroll
  for(int g = 0; g < 4; g++){
    int idx = g * 256 + lane * 4;
    f32x4v e = *(const f32x4v*)(earow + idx);
    unsigned dd4 = *(const unsigned*)(drow + idx);
    float vals[4] = {e.x, e.y, e.z, e.w};
    f32x4v o;
    #pragma unroll
    for(int e2 = 0; e2 < 4; e2++){
      int dd = (dd4 >> (e2 * 8)) & 255;
      float ov = vals[e2] + ((dd != 255) ? w8s[h][dd & 7] : 0.f);
      if(e2 == 0) o.x = ov; else if(e2 == 1) o.y = ov; else if(e2 == 2) o.z = ov; else o.w = ov;
      if(dd == 0) fpart += vals[e2];
    }
    __builtin_nontemporal_store(o, (f32x4v*)(abrow + idx));
  }
  float fsum = wsum(fpart);
  if(lane == 0) fvals[widx] = (cnt > 0) ? fsum / (float)cnt : 0.f;
  // ---- e-prefetch (lines L1-hot from the stream above)
  if(cnt > 0 && cnt <= 64){
    for(int s = lane; s < cnt; s += 64)
      evl[wv][s] = earow[nlist[s]];
  }
  __builtin_amdgcn_wave_barrier();
  // ---- phase B: single-head attention, 8x8 micro-layout
  if(cnt > 0 && cnt <= 64){
    float4 q4 = *(const float4*)&qs[h * 32 + r8 * 4];
    for(int u = 0; u < cnt; u += 8){
      int s = u + g8;
      bool valid = (s < cnt);
      int j = nlist[valid ? s : (cnt - 1)];
      float4 k4 = *(const float4*)(kf + kvbase + (size_t)j * 256 + h * 32 + r8 * 4);
      float prod = k4.x * q4.x + k4.y * q4.y + k4.z * q4.z + k4.w * q4.w;
      prod += __shfl_xor(prod, 1, 64);
      prod += __shfl_xor(prod, 2, 64);
      prod += __shfl_xor(prod, 4, 64);
      if(r8 == 0 && valid) sc[wv][s] = prod * scale + evl[wv][s];
    }
    __builtin_amdgcn_wave_barrier();
    float m = -3.0e38f;
    for(int s = 0; s < cnt; s++) m = fmaxf(m, sc[wv][s]);
    float4 o4 = {0.f, 0.f, 0.f, 0.f};
    float Sp = 0.f;
    for(int u = 0; u < cnt; u += 8){
      int s = u + g8;
      if(s < cnt){
        float p = __expf(sc[wv][s] - m);
        Sp += p;
        int j = nlist[s];
        ushort4 vv = *(const ushort4*)(vb + kvbase + (size_t)j * 256 + h * 32 + r8 * 4);
        o4.x = fmaf(p, b2f(vv.x), o4.x);
        o4.y = fmaf(p, b2f(vv.y), o4.y);
        o4.z = fmaf(p, b2f(vv.z), o4.z);
        o4.w = fmaf(p, b2f(vv.w), o4.w);
      }
    }
    #pragma unroll
    for(int off = 8; off <= 32; off <<= 1){
      o4.x += __shfl_xor(o4.x, off, 64);
      o4.y += __shfl_xor(o4.y, off, 64);
      o4.z += __shfl_xor(o4.z, off, 64);
      o4.w += __shfl_xor(o4.w, off, 64);
      Sp += __shfl_xor(Sp, off, 64);
    }
    if(g8 == 0){
      float invS = 1.f / Sp;
      float4 ov; ov.x = o4.x * invS; ov.y = o4.y * invS; ov.z = o4.z * invS; ov.w = o4.w * invS;
      *(float4*)(aorow + h * 32 + r8 * 4) = ov;
    }
  } else if(cnt > 64){
    // fallback: single-head online softmax with direct ea gather (never hit at 2% density)
    const float* Kb = kf + kvbase + h * 32 + d;
    const u16*   Vb = vb + kvbase + h * 32 + d;
    float q_d = qs[h * 32 + d];
    float S = 0.f, o = 0.f;
    float m = -3.0e38f;
    for(int idx = 0; idx < cnt; idx++){
      int j = nlist[idx];
      float kv = isV ? b2f(Vb[(size_t)j * 256]) : Kb[(size_t)j * 256];
      float prod = isV ? 0.f : kv * q_d;
      #pragma unroll
      for(int off = 16; off >= 1; off >>= 1) prod += __shfl_xor(prod, off, 64);
      float e = earow[j];
      float s2 = __shfl(prod, 0, 64) * scale + e;
      float nm = fmaxf(m, s2);
      float rs = __expf(m - nm);
      float p  = __expf(s2 - nm);
      S = S * rs + p;
      o = o * rs + p * (isV ? kv : 0.f);
      m = nm;
    }
    if(isV) aorow[h * 32 + d] = o / S;
  } else {
    // zero-degree: uniform mean of V
    const u16* Vb = vb + kvbase + h * 32 + d;
    float o = 0.f;
    for(int j2 = half; j2 < 1024; j2 += 2)
      o += b2f(Vb[(size_t)j2 * 256]);
    o += __shfl_xor(o, 32, 64);
    if(lane < 32) aorow[h * 32 + d] = o / 1024.f;
  }
}

// ---------------- x2 = x + ao @ Wo + fs @ Wf — 1024 blocks x 4 rows (NT x2 stores)
__global__ __launch_bounds__(256) void k_outproj(const float* ao, const float* x, const float* fsd,
                                                 const float* Wo, const float* Wf, float* x2){
  __shared__ float as_[4][256];
  __shared__ float fsl[4][8];
  int t = threadIdx.x;
  int rb = blockIdx.x;                       // 1024 blocks x 4 rows
  const float* Ab = ao + (size_t)rb * 4 * 256;
  #pragma unroll
  for(int m = 0; m < 4; m++) as_[m][t] = Ab[m * 256 + t];
  if(t < 32){
    int m = t >> 3, h = t & 7;
    int row = rb * 4 + m;
    int b = row >> 10, i = row & 1023;
    fsl[m][h] = fsd[((((size_t)b << 3) + h) << 10) + i];
  }
  __syncthreads();
  float acc[4];
  #pragma unroll
  for(int r = 0; r < 4; r++) acc[r] = 0.f;
  for(int k4 = 0; k4 < 64; k4++){
    float w0 = Wo[(size_t)(k4 * 4 + 0) * 256 + t];
    float w1 = Wo[(size_t)(k4 * 4 + 1) * 256 + t];
    float w2 = Wo[(size_t)(k4 * 4 + 2) * 256 + t];
    float w3 = Wo[(size_t)(k4 * 4 + 3) * 256 + t];
    #pragma unroll
    for(int r = 0; r < 4; r++){
      float4 av = *(const float4*)&as_[r][k4 * 4];
      acc[r] = fmaf(av.x, w0, fmaf(av.y, w1, fmaf(av.z, w2, fmaf(av.w, w3, acc[r]))));
    }
  }
  float wf[8];
  #pragma unroll
  for(int h = 0; h < 8; h++) wf[h] = Wf[(size_t)h * 256 + t];
  int rowbase = rb * 4;
  #pragma unroll
  for(int r = 0; r < 4; r++){
    int row = rowbase + r;
    float res = acc[r] + x[(size_t)row * 256 + t];
    #pragma unroll
    for(int h = 0; h < 8; h++) res = fmaf(fsl[r][h], wf[h], res);
    __builtin_nontemporal_store(res, &x2[(size_t)row * 256 + t]);
  }
}

extern "C" void kernel_launch(void* const* d_in, const int* in_sizes, int n_in,
                              void* d_out, int out_size, void* d_ws, size_t ws_size,
                              hipStream_t stream) {
  float* out = (float*)d_out;
  float* x2   = out;                 // [4,1024,256]    f32
  float* ab   = out + 1048576;       // [4,8,1024,1024] f32
  float* expl = out + 34603008;      // [4,1024,1024]   f32 (1.0/0.0)

  bool ok = (n_in == 9) &&
            in_sizes[0] == 1048576  &&
            in_sizes[1] == 4194304  &&
            in_sizes[2] == 33554432 &&
            in_sizes[3] == 65536 && in_sizes[4] == 65536 &&
            in_sizes[5] == 65536 && in_sizes[6] == 65536 &&
            in_sizes[7] == 2048  && in_sizes[8] == 64 &&
            out_size == 38797312;
  if(!ok){
    hipLaunchKernelGGL(k_fill, dim3(4096), dim3(256), 0, stream, x2, 1048576u, 1000.0f);
    return;
  }
  if(ws_size < (size_t)20070400){
    hipLaunchKernelGGL(k_fill, dim3(4096), dim3(256), 0, stream, x2, 1048576u, 2000.0f);
    return;
  }

  const float* x   = (const float*)d_in[0];
  const int*   adj = (const int*)d_in[1];
  const float* ea  = (const float*)d_in[2];
  const float* Wq  = (const float*)d_in[3];
  const float* Wk  = (const float*)d_in[4];
  const float* Wv  = (const float*)d_in[5];
  const float* Wo  = (const float*)d_in[6];
  const float* Wf  = (const float*)d_in[7];
  const float* dw  = (const float*)d_in[8];

  char* ws = (char*)d_ws;
  u64*   bits   = (u64*)(ws + 0);           //  512 KB [0, 524288)
  u8*    dist   = (u8*)(ws + 524288);       //    4 MB [524288, 4718592)
  float* qf     = (float*)(ws + 4718592);   //    4 MB [4718592, 8912896)
  float* kf     = (float*)(ws + 8912896);   //    4 MB [8912896, 13107200)
  u16*   vb     = (u16*)(ws + 13107200);    //    2 MB [13107200, 15204352)
  float* ao     = (float*)(ws + 15204352);  //    4 MB [15204352, 19398656)
  float* fvals  = (float*)(ws + 19398656);  //  128 KB [19398656, 19529728)
  u16*   nlistg = (u16*)(ws + 19529728);    //  512 KB [19529728, 20054016)
  int*   cntg   = (int*)(ws + 20054016);    //   16 KB [20054016, 20070400)

  hipLaunchKernelGGL(k_prep,     dim3(1408), dim3(256), 0, stream,
                     x, Wq, Wk, Wv, qf, kf, vb, adj, bits, nlistg, cntg);
  hipLaunchKernelGGL(k_bfs,      dim3(256),  dim3(512), 0, stream, bits, dist, expl);
  hipLaunchKernelGGL(k_biasattn, dim3(4096), dim3(512), 0, stream,
                     bits, ea, dist, dw, qf, kf, vb, nlistg, cntg, ab, ao, fvals);
  hipLaunchKernelGGL(k_outproj,  dim3(1024), dim3(256), 0, stream,
                     ao, x, fvals, Wo, Wf, x2);
}

// Round 34
// 180.052 us; speedup vs baseline: 1.0183x; 1.0183x over previous
//
#include <hip/hip_runtime.h>
#include <stdint.h>

#define NN 1024
#define DD 256
#define KHOPS 8

typedef unsigned short u16;
typedef unsigned long long u64;
typedef unsigned char u8;
typedef float f32x4v __attribute__((ext_vector_type(4)));

__device__ __forceinline__ float b2f(u16 u){ return __uint_as_float(((unsigned int)u) << 16); }
__device__ __forceinline__ u16 f2b(float f){
  unsigned int x = __float_as_uint(f);
  unsigned int r = (x + 0x7FFFu + ((x >> 16) & 1u)) >> 16;
  return (u16)r;
}
__device__ __forceinline__ float wsum(float v){
  #pragma unroll
  for(int off = 32; off >= 1; off >>= 1) v += __shfl_xor(v, off, 64);
  return v;
}

// ---------------- sentinel fill (contract-violation signal), f32
__global__ __launch_bounds__(256) void k_fill(float* p, unsigned n, float v){
  unsigned idx = blockIdx.x * 256 + threadIdx.x;
  if(idx < n) p[idx] = v;
}

// ---------------- merged prelude: blocks 0..383 = staging GEMM, 384..1407 = bitset
__global__ __launch_bounds__(256) void k_prep(const float* X, const float* Wq, const float* Wk,
                                              const float* Wv, float* qf, float* kf, u16* vb,
                                              const int* adj, u64* bits){
  __shared__ float xs[32][256];
  int t = threadIdx.x;
  if(blockIdx.x >= 384){
    int vblk = blockIdx.x - 384;
    int row = vblk * 4 + (t >> 6);
    int lane = t & 63;
    const int* ar = adj + (size_t)row * NN;
    #pragma unroll
    for(int w = 0; w < 16; w++){
      u64 msk = __ballot(ar[w * 64 + lane] != 0);
      if(lane == 0) bits[(size_t)row * 16 + w] = msk;
    }
    return;
  }
  int proj = blockIdx.x >> 7;
  int rb = blockIdx.x & 127;
  const float* W = (proj == 0) ? Wq : (proj == 1) ? Wk : Wv;
  const float* Xb = X + (size_t)rb * 32 * 256;
  #pragma unroll
  for(int m = 0; m < 32; m++) xs[m][t] = Xb[m * 256 + t];
  __syncthreads();
  float acc[32];
  #pragma unroll
  for(int r = 0; r < 32; r++) acc[r] = 0.f;
  for(int k4 = 0; k4 < 64; k4++){
    float w0 = W[(size_t)(k4 * 4 + 0) * 256 + t];
    float w1 = W[(size_t)(k4 * 4 + 1) * 256 + t];
    float w2 = W[(size_t)(k4 * 4 + 2) * 256 + t];
    float w3 = W[(size_t)(k4 * 4 + 3) * 256 + t];
    #pragma unroll
    for(int r = 0; r < 32; r++){
      float4 xv = *(const float4*)&xs[r][k4 * 4];
      acc[r] = fmaf(xv.x, w0, fmaf(xv.y, w1, fmaf(xv.z, w2, fmaf(xv.w, w3, acc[r]))));
    }
  }
  int rowbase = rb * 32;
  if(proj == 2){
    for(int r = 0; r < 32; r++) vb[(size_t)(rowbase + r) * 256 + t] = f2b(acc[r]);
  } else {
    float* dst = (proj == 0) ? qf : kf;
    for(int r = 0; r < 32; r++) dst[(size_t)(rowbase + r) * 256 + t] = acc[r];
  }
}

// ---------------- frontier BFS with LDS-resident adjacency (R29-verbatim, 512 thr)
__global__ __launch_bounds__(512) void k_bfs(const u64* bits, u8* dist, float* expl){
  __shared__ __attribute__((aligned(16))) u64 asw[16384];
  __shared__ __attribute__((aligned(16))) u8 drow4[8][1024];
  __shared__ u64 red4[8][16];
  int tid = threadIdx.x;
  int wv = tid >> 6, lane = tid & 63;
  int batch = blockIdx.x >> 6;
  int rowbase = (blockIdx.x & 63) * 16;
  const u64* bb = bits + (((size_t)batch << 10)) * 16;
  for(int g = tid; g < 8192; g += 512){
    int j = g >> 3, c = g & 7;
    ulonglong2 v = *(const ulonglong2*)(bb + (size_t)j * 16 + c * 2);
    int ce = c ^ (j & 7);
    *(ulonglong2*)(&asw[j * 16 + ce * 2]) = v;
  }
  __syncthreads();
  int s = lane & 7;
  for(int rr = 0; rr < 2; rr++){
    int row_local = rowbase + wv * 2 + rr;
    int row = (batch << 10) + row_local;
    u64 vis[16], cur[16];
    {
      const u64* p = asw + row_local * 16;
      int sr = row_local & 7;
      #pragma unroll
      for(int c = 0; c < 8; c++){
        ulonglong2 v = *(const ulonglong2*)(p + (((c ^ sr)) << 1));
        vis[2*c] = v.x; vis[2*c+1] = v.y;
        cur[2*c] = v.x; cur[2*c+1] = v.y;
      }
    }
    { int4 ff; ff.x = ff.y = ff.z = ff.w = -1; ((int4*)drow4[wv])[lane] = ff; }
    __builtin_amdgcn_wave_barrier();
    #pragma unroll
    for(int it = 0; it < 16; it++)
      if((cur[it] >> lane) & 1) drow4[wv][it * 64 + lane] = 0;
    for(int k = 1; k < KHOPS; k++){
      unsigned mymask = 0;
      #pragma unroll
      for(int it = 0; it < 16; it++) mymask |= ((unsigned)((cur[it] >> lane) & 1)) << it;
      u64 acc[16];
      #pragma unroll
      for(int w = 0; w < 16; w++) acc[w] = 0;
      while(mymask){
        int it0 = __builtin_ctz(mymask); mymask &= mymask - 1;
        int it1 = it0;
        if(mymask){ it1 = __builtin_ctz(mymask); mymask &= mymask - 1; }
        const u64* pA = asw + (it0 * 64 + lane) * 16;
        const u64* pB = asw + (it1 * 64 + lane) * 16;
        ulonglong2 a0 = *(const ulonglong2*)(pA + ((0^s)<<1)), b0 = *(const ulonglong2*)(pB + ((0^s)<<1));
        ulonglong2 a1 = *(const ulonglong2*)(pA + ((1^s)<<1)), b1 = *(const ulonglong2*)(pB + ((1^s)<<1));
        ulonglong2 a2 = *(const ulonglong2*)(pA + ((2^s)<<1)), b2 = *(const ulonglong2*)(pB + ((2^s)<<1));
        ulonglong2 a3 = *(const ulonglong2*)(pA + ((3^s)<<1)), b3 = *(const ulonglong2*)(pB + ((3^s)<<1));
        ulonglong2 a4 = *(const ulonglong2*)(pA + ((4^s)<<1)), b4 = *(const ulonglong2*)(pB + ((4^s)<<1));
        ulonglong2 a5 = *(const ulonglong2*)(pA + ((5^s)<<1)), b5 = *(const ulonglong2*)(pB + ((5^s)<<1));
        ulonglong2 a6 = *(const ulonglong2*)(pA + ((6^s)<<1)), b6 = *(const ulonglong2*)(pB + ((6^s)<<1));
        ulonglong2 a7 = *(const ulonglong2*)(pA + ((7^s)<<1)), b7 = *(const ulonglong2*)(pB + ((7^s)<<1));
        acc[0]  |= a0.x | b0.x;  acc[1]  |= a0.y | b0.y;
        acc[2]  |= a1.x | b1.x;  acc[3]  |= a1.y | b1.y;
        acc[4]  |= a2.x | b2.x;  acc[5]  |= a2.y | b2.y;
        acc[6]  |= a3.x | b3.x;  acc[7]  |= a3.y | b3.y;
        acc[8]  |= a4.x | b4.x;  acc[9]  |= a4.y | b4.y;
        acc[10] |= a5.x | b5.x;  acc[11] |= a5.y | b5.y;
        acc[12] |= a6.x | b6.x;  acc[13] |= a6.y | b6.y;
        acc[14] |= a7.x | b7.x;  acc[15] |= a7.y | b7.y;
      }
      #pragma unroll
      for(int w = 0; w < 16; w++){
        acc[w] |= __shfl_xor(acc[w], 16, 64);
        acc[w] |= __shfl_xor(acc[w], 32, 64);
      }
      int g4 = lane >> 4;
      u64 r0, r1, r2, r3;
      if(g4 == 0){ r0 = acc[0];  r1 = acc[1];  r2 = acc[2];  r3 = acc[3];  }
      else if(g4 == 1){ r0 = acc[4];  r1 = acc[5];  r2 = acc[6];  r3 = acc[7];  }
      else if(g4 == 2){ r0 = acc[8];  r1 = acc[9];  r2 = acc[10]; r3 = acc[11]; }
      else            { r0 = acc[12]; r1 = acc[13]; r2 = acc[14]; r3 = acc[15]; }
      #pragma unroll
      for(int off = 1; off <= 8; off <<= 1){
        r0 |= __shfl_xor(r0, off, 64);
        r1 |= __shfl_xor(r1, off, 64);
        r2 |= __shfl_xor(r2, off, 64);
        r3 |= __shfl_xor(r3, off, 64);
      }
      int sub = lane & 15;
      if(sub == 0)      red4[wv][g4 * 4 + 0] = r0;
      else if(sub == 1) red4[wv][g4 * 4 + 1] = r1;
      else if(sub == 2) red4[wv][g4 * 4 + 2] = r2;
      else if(sub == 3) red4[wv][g4 * 4 + 3] = r3;
      __builtin_amdgcn_wave_barrier();
      u64 any = 0, andv = ~0ull;
      #pragma unroll
      for(int w = 0; w < 16; w++){
        u64 nv = red4[wv][w];
        u64 nw = nv & ~vis[w];
        vis[w] |= nw;
        cur[w] = nw;
        any |= nw;
        andv &= vis[w];
      }
      __builtin_amdgcn_wave_barrier();
      if(any == 0) break;
      #pragma unroll
      for(int it = 0; it < 16; it++)
        if((cur[it] >> lane) & 1) drow4[wv][it * 64 + lane] = (u8)k;
      if(andv == ~0ull) break;
    }
    __builtin_amdgcn_wave_barrier();
    ((int4*)(dist + (size_t)row * NN))[lane] = ((const int4*)drow4[wv])[lane];
    float* eo = expl + (size_t)row * NN;
    #pragma unroll
    for(int it = 0; it < 16; it++){
      int j = it * 64 + lane;
      eo[j] = ((vis[it] >> lane) & 1) ? 1.0f : 0.0f;
    }
  }
}

// ---------------- FUSED bias + attention (dual-head); writes ao + fvals (R30-verbatim)
__global__ __launch_bounds__(256) void k_biasattn(
    const u64* bits, const float* ea, const u8* dist, const float* dw,
    const float* qf, const float* kf, const u16* vb,
    float* ab_out, float* ao, float* fvals)
{
  __shared__ float qs[256];
  __shared__ u16 nlist[1024];
  __shared__ float sc0[4][64], sc1[4][64];
  __shared__ float evl0[4][64], evl1[4][64];
  __shared__ float w8s[8][8];          // w8s[h][k] = dw[k][h]
  __shared__ u64 wm[16];
  __shared__ int bs[16];
  __shared__ int ncnt_s;
  int t = threadIdx.x, wv = t >> 6, lane = t & 63;
  int bi = blockIdx.x, b = bi >> 10, i = bi & 1023;
  qs[t] = qf[(size_t)bi * 256 + t];
  if(t < 64) w8s[t & 7][t >> 3] = dw[(t >> 3) * 8 + (t & 7)];
  if(wv == 0){
    if(lane < 16) wm[lane] = bits[(size_t)bi * 16 + lane];
    __builtin_amdgcn_wave_barrier();
    if(lane == 0){
      int run = 0;
      #pragma unroll
      for(int it = 0; it < 16; it++){ bs[it] = run; run += __popcll(wm[it]); }
      ncnt_s = run;
    }
    __builtin_amdgcn_wave_barrier();
    if(lane < 16){
      u64 w = wm[lane];
      int pos = bs[lane];
      while(w){
        int bpos = __builtin_ctzll(w);
        nlist[pos++] = (u16)(lane * 64 + bpos);
        w &= w - 1;
      }
    }
  }
  __syncthreads();
  int cnt = ncnt_s;
  const float scale = 0.17677669529663687f;   // 1/sqrt(32)
  int d = lane & 31;
  int half = lane >> 5;
  bool isV = (lane >= 32);
  int g8 = lane >> 3, r8 = lane & 7;
  size_t kvbase = ((size_t)(b << 10)) * 256;
  const u8* drow = dist + (size_t)bi * NN;
  float* aorow = ao + (size_t)bi * 256;
  int h0 = wv * 2, h1 = wv * 2 + 1;
  int widx0 = (((b << 3) + h0) << 10) + i;
  int widx1 = (((b << 3) + h1) << 10) + i;
  const float* earow0 = ea + (size_t)widx0 * NN;
  const float* earow1 = ea + (size_t)widx1 * NN;
  float* abrow0 = ab_out + (size_t)widx0 * NN;
  float* abrow1 = ab_out + (size_t)widx1 * NN;
  // ---- phase A: dual-head bias stream (dd4 loaded once; NT stores)
  float fpart0 = 0.f, fpart1 = 0.f;
  #pragma unroll
  for(int g = 0; g < 4; g++){
    int idx = g * 256 + lane * 4;
    f32x4v e0 = *(const f32x4v*)(earow0 + idx);
    f32x4v e1 = *(const f32x4v*)(earow1 + idx);
    unsigned dd4 = *(const unsigned*)(drow + idx);
    float v0[4] = {e0.x, e0.y, e0.z, e0.w};
    float v1[4] = {e1.x, e1.y, e1.z, e1.w};
    f32x4v o0, o1;
    #pragma unroll
    for(int e2 = 0; e2 < 4; e2++){
      int dd = (dd4 >> (e2 * 8)) & 255;
      float w0 = (dd != 255) ? w8s[h0][dd & 7] : 0.f;
      float w1 = (dd != 255) ? w8s[h1][dd & 7] : 0.f;
      float ov0 = v0[e2] + w0, ov1 = v1[e2] + w1;
      if(e2 == 0){ o0.x = ov0; o1.x = ov1; }
      else if(e2 == 1){ o0.y = ov0; o1.y = ov1; }
      else if(e2 == 2){ o0.z = ov0; o1.z = ov1; }
      else { o0.w = ov0; o1.w = ov1; }
      if(dd == 0){ fpart0 += v0[e2]; fpart1 += v1[e2]; }
    }
    __builtin_nontemporal_store(o0, (f32x4v*)(abrow0 + idx));
    __builtin_nontemporal_store(o1, (f32x4v*)(abrow1 + idx));
  }
  float fsum0 = wsum(fpart0);
  float fsum1 = wsum(fpart1);
  if(lane == 0){
    fvals[widx0] = (cnt > 0) ? fsum0 / (float)cnt : 0.f;
    fvals[widx1] = (cnt > 0) ? fsum1 / (float)cnt : 0.f;
  }
  // ---- e-prefetch for both heads (lines L1-hot from phase A)
  if(cnt > 0 && cnt <= 64){
    for(int s = lane; s < cnt; s += 64){
      int j = nlist[s];
      evl0[wv][s] = earow0[j];
      evl1[wv][s] = earow1[j];
    }
  }
  __builtin_amdgcn_wave_barrier();
  // ---- phase B: attention (writes ao directly)
  if(cnt > 0 && cnt <= 64){
    float4 q40 = *(const float4*)&qs[h0 * 32 + r8 * 4];
    float4 q41 = *(const float4*)&qs[h1 * 32 + r8 * 4];
    for(int u = 0; u < cnt; u += 8){
      int s = u + g8;
      bool valid = (s < cnt);
      int j = nlist[valid ? s : (cnt - 1)];
      const float* krow = kf + kvbase + (size_t)j * 256;
      float4 k40 = *(const float4*)(krow + h0 * 32 + r8 * 4);
      float4 k41 = *(const float4*)(krow + h1 * 32 + r8 * 4);
      float p0 = k40.x * q40.x + k40.y * q40.y + k40.z * q40.z + k40.w * q40.w;
      float p1 = k41.x * q41.x + k41.y * q41.y + k41.z * q41.z + k41.w * q41.w;
      p0 += __shfl_xor(p0, 1, 64);  p1 += __shfl_xor(p1, 1, 64);
      p0 += __shfl_xor(p0, 2, 64);  p1 += __shfl_xor(p1, 2, 64);
      p0 += __shfl_xor(p0, 4, 64);  p1 += __shfl_xor(p1, 4, 64);
      if(r8 == 0 && valid){
        sc0[wv][s] = p0 * scale + evl0[wv][s];
        sc1[wv][s] = p1 * scale + evl1[wv][s];
      }
    }
    __builtin_amdgcn_wave_barrier();
    float m0 = -3.0e38f, m1 = -3.0e38f;
    for(int s = 0; s < cnt; s++){ m0 = fmaxf(m0, sc0[wv][s]); m1 = fmaxf(m1, sc1[wv][s]); }
    float4 o40 = {0.f,0.f,0.f,0.f}, o41 = {0.f,0.f,0.f,0.f};
    float Sp0 = 0.f, Sp1 = 0.f;
    for(int u = 0; u < cnt; u += 8){
      int s = u + g8;
      if(s < cnt){
        float p0 = __expf(sc0[wv][s] - m0);
        float p1 = __expf(sc1[wv][s] - m1);
        Sp0 += p0; Sp1 += p1;
        int j = nlist[s];
        const u16* vrow = vb + kvbase + (size_t)j * 256;
        ushort4 vv0 = *(const ushort4*)(vrow + h0 * 32 + r8 * 4);
        ushort4 vv1 = *(const ushort4*)(vrow + h1 * 32 + r8 * 4);
        o40.x = fmaf(p0, b2f(vv0.x), o40.x);  o41.x = fmaf(p1, b2f(vv1.x), o41.x);
        o40.y = fmaf(p0, b2f(vv0.y), o40.y);  o41.y = fmaf(p1, b2f(vv1.y), o41.y);
        o40.z = fmaf(p0, b2f(vv0.z), o40.z);  o41.z = fmaf(p1, b2f(vv1.z), o41.z);
        o40.w = fmaf(p0, b2f(vv0.w), o40.w);  o41.w = fmaf(p1, b2f(vv1.w), o41.w);
      }
    }
    #pragma unroll
    for(int off = 8; off <= 32; off <<= 1){
      o40.x += __shfl_xor(o40.x, off, 64);  o41.x += __shfl_xor(o41.x, off, 64);
      o40.y += __shfl_xor(o40.y, off, 64);  o41.y += __shfl_xor(o41.y, off, 64);
      o40.z += __shfl_xor(o40.z, off, 64);  o41.z += __shfl_xor(o41.z, off, 64);
      o40.w += __shfl_xor(o40.w, off, 64);  o41.w += __shfl_xor(o41.w, off, 64);
      Sp0 += __shfl_xor(Sp0, off, 64);      Sp1 += __shfl_xor(Sp1, off, 64);
    }
    if(g8 == 0){
      float iS0 = 1.f / Sp0, iS1 = 1.f / Sp1;
      float4 ov0; ov0.x = o40.x * iS0; ov0.y = o40.y * iS0; ov0.z = o40.z * iS0; ov0.w = o40.w * iS0;
      float4 ov1; ov1.x = o41.x * iS1; ov1.y = o41.y * iS1; ov1.z = o41.z * iS1; ov1.w = o41.w * iS1;
      *(float4*)(aorow + h0 * 32 + r8 * 4) = ov0;
      *(float4*)(aorow + h1 * 32 + r8 * 4) = ov1;
    }
  } else if(cnt > 64){
    // fallback: per-head online softmax with direct ea gather (never hit at 2% density)
    #pragma unroll
    for(int hh = 0; hh < 2; hh++){
      int h = wv * 2 + hh;
      const float* earow = (hh == 0) ? earow0 : earow1;
      const float* Kb = kf + kvbase + h * 32 + d;
      const u16*   Vb = vb + kvbase + h * 32 + d;
      float q_d = qs[h * 32 + d];
      float S = 0.f, o = 0.f;
      float m = -3.0e38f;
      for(int idx = 0; idx < cnt; idx++){
        int j = nlist[idx];
        float kv = isV ? b2f(Vb[(size_t)j * 256]) : Kb[(size_t)j * 256];
        float prod = isV ? 0.f : kv * q_d;
        #pragma unroll
        for(int off = 16; off >= 1; off >>= 1) prod += __shfl_xor(prod, off, 64);
        float e = earow[j];
        float s2 = __shfl(prod, 0, 64) * scale + e;
        float nm = fmaxf(m, s2);
        float rs = __expf(m - nm);
        float p  = __expf(s2 - nm);
        S = S * rs + p;
        o = o * rs + p * (isV ? kv : 0.f);
        m = nm;
      }
      if(isV) aorow[h * 32 + d] = o / S;
    }
  } else {
    // zero-degree: uniform mean of V
    #pragma unroll
    for(int hh = 0; hh < 2; hh++){
      int h = wv * 2 + hh;
      const u16* Vb = vb + kvbase + h * 32 + d;
      float o = 0.f;
      for(int j2 = half; j2 < 1024; j2 += 2)
        o += b2f(Vb[(size_t)j2 * 256]);
      o += __shfl_xor(o, 32, 64);
      if(lane < 32) aorow[h * 32 + d] = o / 1024.f;
    }
  }
}

// ---------------- x2 = x + ao @ Wo + fs @ Wf — 1024 blocks x 4 rows (16 waves/CU)
__global__ __launch_bounds__(256) void k_outproj(const float* ao, const float* x, const float* fsd,
                                                 const float* Wo, const float* Wf, float* x2){
  __shared__ float as_[4][256];
  __shared__ float fsl[4][8];
  int t = threadIdx.x;
  int rb = blockIdx.x;                       // 1024 blocks x 4 rows
  const float* Ab = ao + (size_t)rb * 4 * 256;
  #pragma unroll
  for(int m = 0; m < 4; m++) as_[m][t] = Ab[m * 256 + t];
  if(t < 32){
    int m = t >> 3, h = t & 7;
    int row = rb * 4 + m;
    int b = row >> 10, i = row & 1023;
    fsl[m][h] = fsd[((((size_t)b << 3) + h) << 10) + i];
  }
  __syncthreads();
  float acc[4];
  #pragma unroll
  for(int r = 0; r < 4; r++) acc[r] = 0.f;
  for(int k4 = 0; k4 < 64; k4++){
    float w0 = Wo[(size_t)(k4 * 4 + 0) * 256 + t];
    float w1 = Wo[(size_t)(k4 * 4 + 1) * 256 + t];
    float w2 = Wo[(size_t)(k4 * 4 + 2) * 256 + t];
    float w3 = Wo[(size_t)(k4 * 4 + 3) * 256 + t];
    #pragma unroll
    for(int r = 0; r < 4; r++){
      float4 av = *(const float4*)&as_[r][k4 * 4];
      acc[r] = fmaf(av.x, w0, fmaf(av.y, w1, fmaf(av.z, w2, fmaf(av.w, w3, acc[r]))));
    }
  }
  float wf[8];
  #pragma unroll
  for(int h = 0; h < 8; h++) wf[h] = Wf[(size_t)h * 256 + t];
  int rowbase = rb * 4;
  #pragma unroll
  for(int r = 0; r < 4; r++){
    int row = rowbase + r;
    float res = acc[r] + x[(size_t)row * 256 + t];
    #pragma unroll
    for(int h = 0; h < 8; h++) res = fmaf(fsl[r][h], wf[h], res);
    x2[(size_t)row * 256 + t] = res;
  }
}

extern "C" void kernel_launch(void* const* d_in, const int* in_sizes, int n_in,
                              void* d_out, int out_size, void* d_ws, size_t ws_size,
                              hipStream_t stream) {
  float* out = (float*)d_out;
  float* x2   = out;                 // [4,1024,256]    f32
  float* ab   = out + 1048576;       // [4,8,1024,1024] f32
  float* expl = out + 34603008;      // [4,1024,1024]   f32 (1.0/0.0)

  bool ok = (n_in == 9) &&
            in_sizes[0] == 1048576  &&
            in_sizes[1] == 4194304  &&
            in_sizes[2] == 33554432 &&
            in_sizes[3] == 65536 && in_sizes[4] == 65536 &&
            in_sizes[5] == 65536 && in_sizes[6] == 65536 &&
            in_sizes[7] == 2048  && in_sizes[8] == 64 &&
            out_size == 38797312;
  if(!ok){
    hipLaunchKernelGGL(k_fill, dim3(4096), dim3(256), 0, stream, x2, 1048576u, 1000.0f);
    return;
  }
  if(ws_size < (size_t)19791872){
    hipLaunchKernelGGL(k_fill, dim3(4096), dim3(256), 0, stream, x2, 1048576u, 2000.0f);
    return;
  }

  const float* x   = (const float*)d_in[0];
  const int*   adj = (const int*)d_in[1];
  const float* ea  = (const float*)d_in[2];
  const float* Wq  = (const float*)d_in[3];
  const float* Wk  = (const float*)d_in[4];
  const float* Wv  = (const float*)d_in[5];
  const float* Wo  = (const float*)d_in[6];
  const float* Wf  = (const float*)d_in[7];
  const float* dw  = (const float*)d_in[8];

  char* ws = (char*)d_ws;
  u64*   bits  = (u64*)(ws + 0);           //  512 KB [0, 524288)
  u8*    dist  = (u8*)(ws + 524288);       //    4 MB [524288, 4718592)
  float* qf    = (float*)(ws + 4718592);   //    4 MB [4718592, 8912896)
  float* kf    = (float*)(ws + 8912896);   //    4 MB [8912896, 13107200)
  u16*   vb    = (u16*)(ws + 13107200);    //    2 MB [13107200, 15204352)
  float* ao    = (float*)(ws + 15204352);  //    4 MB [15204352, 19398656)
  float* fvals = (float*)(ws + 19398656);  //  128 KB [19398656, 19529728)

  hipLaunchKernelGGL(k_prep,     dim3(1408), dim3(256), 0, stream,
                     x, Wq, Wk, Wv, qf, kf, vb, adj, bits);
  hipLaunchKernelGGL(k_bfs,      dim3(256),  dim3(512), 0, stream, bits, dist, expl);
  hipLaunchKernelGGL(k_biasattn, dim3(4096), dim3(256), 0, stream,
                     bits, ea, dist, dw, qf, kf, vb, ab, ao, fvals);
  hipLaunchKernelGGL(k_outproj,  dim3(1024), dim3(256), 0, stream,
                     ao, x, fvals, Wo, Wf, x2);
}